// Round 5
// baseline (53.065 us; speedup 1.0000x reference)
//
#include <hip/hip_runtime.h>
#include <hip/hip_bf16.h>

#define NN 6400   // total nodes
#define NG 200    // nodes per graph
#define NB 32     // graphs
#define FF 128    // F_in == F_out
#define MAGICF 0x5E11C0DEu

typedef __attribute__((ext_vector_type(8))) short s8v;  // 8 x bf16 (4 VGPRs)
typedef __attribute__((ext_vector_type(4))) float f4v;  // MFMA accumulator

__device__ __forceinline__ short f2bf(float x) {
  unsigned u = __float_as_uint(x);
  u += 0x7FFFu + ((u >> 16) & 1u);   // RNE
  return (short)(u >> 16);
}

// Bank-swizzle for LDS fragment granules (bijective per 64-granule tile).
__device__ __forceinline__ int swz(int g) {
  return g ^ ((g >> 4) & 3) ^ ((g >> 6) & 7);
}

// supp fragment layout: [b][kc=7][nt=8][lane=64][e=8] bf16 (K padded to 224)
__device__ __forceinline__ size_t supp_elem(int b, int kloc, int n) {
  return ((((size_t)b * 7 + (kloc >> 5)) * 8 + (n >> 4)) * 64
          + (n & 15) + ((kloc >> 3) & 3) * 16) * 8 + (kloc & 7);
}

// ---------------------------------------------------------------------------
// Single fused kernel, 488 blocks:
//   0..199  : PRODUCER  — msk row + support = feat @ W (MFMA) -> bf16 B-frags
//   200..231: PAD       — zero-fill K-pad (k=200..223) supp fragment slots
//   232..487: CONSUMER  — prefetch adj+sigmoid (overlaps producers), spin on
//             flags, build M A-frags in LDS, MFMA against supp, store out.
// All 488 blocks are co-resident (32 KB LDS -> >=4 blocks/CU), so the spin
// cannot deadlock regardless of dispatch order.
// ---------------------------------------------------------------------------
__global__ __launch_bounds__(256) void fused_kernel(
    const float* __restrict__ feat, const float* __restrict__ weight,
    const float* __restrict__ rew, const float* __restrict__ adj,
    short* __restrict__ supp, float* __restrict__ msk,
    unsigned* __restrict__ flags, float* __restrict__ out)
{
  __shared__ char lds_raw[32768];
  const int t = threadIdx.x;
  const int bid = blockIdx.x;

  if (bid < 200) {                       // ================ PRODUCER ================
    s8v* sW = (s8v*)lds_raw;             // W B-frags [kc=4][nt=8][lane=64]

    // msk row r = bid: 0.5(R+R^T)+I, zero-padded to 224 cols
    {
      const int r = bid;
      if (t < 224) {
        float v = 0.f;
        if (t < 200)
          v = 0.5f * (rew[r * NG + t] + rew[t * NG + r]) + (r == t ? 1.f : 0.f);
        msk[r * 224 + t] = v;
      }
    }

    // stage W fragments (global reads coalesced across lanes per e)
    for (int p = 0; p < 8; ++p) {
      const int idx = t + p * 256;
      const int n = idx & 127, kg = idx >> 7;
      s8v v;
#pragma unroll
      for (int e = 0; e < 8; ++e)
        v[e] = f2bf(weight[(kg * 8 + e) * FF + n]);
      sW[((kg >> 2) * 8 + (n >> 4)) * 64 + (n & 15) + (kg & 3) * 16] = v;
    }
    __syncthreads();

    const int w = t >> 6, l = t & 63;
    const int mt = w >> 1, nh = w & 1;
    const int arow = bid * 32 + mt * 16 + (l & 15);
    const int klane = (l >> 4) * 8;

    f4v acc0 = {0.f,0.f,0.f,0.f}, acc1 = acc0, acc2 = acc0, acc3 = acc0;
#pragma unroll
    for (int kc = 0; kc < 4; ++kc) {
      const float* fp = feat + (size_t)arow * FF + kc * 32 + klane;
      const float4 fa = *(const float4*)fp;
      const float4 fb = *(const float4*)(fp + 4);
      s8v af;
      af[0]=f2bf(fa.x); af[1]=f2bf(fa.y); af[2]=f2bf(fa.z); af[3]=f2bf(fa.w);
      af[4]=f2bf(fb.x); af[5]=f2bf(fb.y); af[6]=f2bf(fb.z); af[7]=f2bf(fb.w);
      acc0 = __builtin_amdgcn_mfma_f32_16x16x32_bf16(af, sW[(kc*8 + nh*4 + 0)*64 + l], acc0, 0,0,0);
      acc1 = __builtin_amdgcn_mfma_f32_16x16x32_bf16(af, sW[(kc*8 + nh*4 + 1)*64 + l], acc1, 0,0,0);
      acc2 = __builtin_amdgcn_mfma_f32_16x16x32_bf16(af, sW[(kc*8 + nh*4 + 2)*64 + l], acc2, 0,0,0);
      acc3 = __builtin_amdgcn_mfma_f32_16x16x32_bf16(af, sW[(kc*8 + nh*4 + 3)*64 + l], acc3, 0,0,0);
    }

    // scatter-store acc as bf16 B-fragments (D: col=l&15, row=(l>>4)*4+reg)
#pragma unroll
    for (int reg = 0; reg < 4; ++reg) {
      const int rr = bid * 32 + mt * 16 + (l >> 4) * 4 + reg;
      const unsigned bb = (unsigned)rr / 200u;
      const int kloc = rr - (int)bb * 200;
      const int n0 = nh * 64 + (l & 15);
      supp[supp_elem(bb, kloc, n0)]      = f2bf(acc0[reg]);
      supp[supp_elem(bb, kloc, n0 + 16)] = f2bf(acc1[reg]);
      supp[supp_elem(bb, kloc, n0 + 32)] = f2bf(acc2[reg]);
      supp[supp_elem(bb, kloc, n0 + 48)] = f2bf(acc3[reg]);
    }

    __threadfence();                     // each thread: own stores device-visible
    __syncthreads();
    if (t == 0)
      __hip_atomic_store(&flags[bid], MAGICF, __ATOMIC_RELEASE,
                         __HIP_MEMORY_SCOPE_AGENT);
    return;
  }

  if (bid < 232) {                       // ================ PAD-ZERO ================
    const int b = bid - 200;
    const size_t base = (((size_t)b * 7 + 6) * 8) * 512;  // [b][kc=6][0][0][0]
    for (int q = t; q < 1536; q += 256) {
      const int nt = q / 192, p = q - nt * 192;
      unsigned* dst = (unsigned*)(supp + base + (size_t)nt * 512 + 128) + p;
      *dst = 0u;
    }
    __threadfence();
    __syncthreads();
    if (t == 0)
      __hip_atomic_store(&flags[bid], MAGICF, __ATOMIC_RELEASE,
                         __HIP_MEMORY_SCOPE_AGENT);
    return;
  }

  // ================ CONSUMER ================
  const int m = bid - 232;
  const int sw2 = (m & 7) * 32 + (m >> 3);  // colocate a graph's 8 slabs per XCD
  const int b = sw2 >> 3, slab = sw2 & 7;
  const int i0 = slab * 25;

  // Phase A0 (independent of producers): prefetch adj, compute sigmoid -> regs.
  float sg[4][8];
  bool okf[4];
#pragma unroll
  for (int p = 0; p < 4; ++p) {
    const int idx = t + p * 256;
    const int i = idx / 28, jg = idx - i * 28;
    const int gi = i0 + i;
    okf[p] = (idx < 896) & (jg < 25) & (gi < 200);
    if (okf[p]) {
      const float* ap = adj + ((size_t)(b * NG + gi) * NN + b * NG + jg * 8);
      const float4 a0 = *(const float4*)ap;
      const float4 a1 = *(const float4*)(ap + 4);
      sg[p][0] = __builtin_amdgcn_rcpf(1.f + __expf(-a0.x));
      sg[p][1] = __builtin_amdgcn_rcpf(1.f + __expf(-a0.y));
      sg[p][2] = __builtin_amdgcn_rcpf(1.f + __expf(-a0.z));
      sg[p][3] = __builtin_amdgcn_rcpf(1.f + __expf(-a0.w));
      sg[p][4] = __builtin_amdgcn_rcpf(1.f + __expf(-a1.x));
      sg[p][5] = __builtin_amdgcn_rcpf(1.f + __expf(-a1.y));
      sg[p][6] = __builtin_amdgcn_rcpf(1.f + __expf(-a1.z));
      sg[p][7] = __builtin_amdgcn_rcpf(1.f + __expf(-a1.w));
    } else {
#pragma unroll
      for (int e = 0; e < 8; ++e) sg[p][e] = 0.f;
    }
  }
  asm volatile("" ::: "memory");         // keep prefetch issued before the spin

  // Wait for all producers + pad blocks.
  if (t < 232) {
    while (__hip_atomic_load(&flags[t], __ATOMIC_ACQUIRE,
                             __HIP_MEMORY_SCOPE_AGENT) != MAGICF)
      __builtin_amdgcn_s_sleep(1);
  }
  __syncthreads();

  // Phase A1: multiply by msk, write M A-fragments to LDS (swizzled).
  s8v* sM = (s8v*)lds_raw;               // [mt=2][kc=7][lane=64], 14 KB
#pragma unroll
  for (int p = 0; p < 4; ++p) {
    const int idx = t + p * 256;
    if (idx < 896) {
      const int i = idx / 28, jg = idx - i * 28;
      const int gi = i0 + i;
      s8v v = {0,0,0,0,0,0,0,0};
      if (okf[p]) {
        const float* mp = msk + gi * 224 + jg * 8;
        const float4 m0 = *(const float4*)mp;
        const float4 m1 = *(const float4*)(mp + 4);
        v[0] = f2bf(m0.x * sg[p][0]);
        v[1] = f2bf(m0.y * sg[p][1]);
        v[2] = f2bf(m0.z * sg[p][2]);
        v[3] = f2bf(m0.w * sg[p][3]);
        v[4] = f2bf(m1.x * sg[p][4]);
        v[5] = f2bf(m1.y * sg[p][5]);
        v[6] = f2bf(m1.z * sg[p][6]);
        v[7] = f2bf(m1.w * sg[p][7]);
      }
      const int g = ((i >> 4) * 7 + (jg >> 2)) * 64 + (i & 15) + (jg & 3) * 16;
      sM[swz(g)] = v;
    }
  }
  __syncthreads();

  // Phase B: 7 K-chunks x 4 N-tiles of MFMA against supp B-frags (global, L2/L3).
  const int w = t >> 6, l = t & 63;
  const int mt = w >> 1, nh = w & 1;
  const s8v* sb = (const s8v*)supp + (size_t)b * 7 * 8 * 64 + (nh * 4) * 64 + l;

  f4v acc0 = {0.f,0.f,0.f,0.f}, acc1 = acc0, acc2 = acc0, acc3 = acc0;
#pragma unroll
  for (int kc = 0; kc < 7; ++kc) {
    const s8v af = sM[swz((mt * 7 + kc) * 64 + l)];
    acc0 = __builtin_amdgcn_mfma_f32_16x16x32_bf16(af, sb[(kc*8 + 0)*64], acc0, 0,0,0);
    acc1 = __builtin_amdgcn_mfma_f32_16x16x32_bf16(af, sb[(kc*8 + 1)*64], acc1, 0,0,0);
    acc2 = __builtin_amdgcn_mfma_f32_16x16x32_bf16(af, sb[(kc*8 + 2)*64], acc2, 0,0,0);
    acc3 = __builtin_amdgcn_mfma_f32_16x16x32_bf16(af, sb[(kc*8 + 3)*64], acc3, 0,0,0);
  }

  // store (guard: only first 25 computed rows are real)
#pragma unroll
  for (int reg = 0; reg < 4; ++reg) {
    const int rl = mt * 16 + (l >> 4) * 4 + reg;
    if (rl < 25) {
      const size_t o = (size_t)(b * NG + i0 + rl) * FF + nh * 64 + (l & 15);
      out[o]      = acc0[reg];
      out[o + 16] = acc1[reg];
      out[o + 32] = acc2[reg];
      out[o + 48] = acc3[reg];
    }
  }
}

// ---------------------------------------------------------------------------
extern "C" void kernel_launch(void* const* d_in, const int* in_sizes, int n_in,
                              void* d_out, int out_size, void* d_ws, size_t ws_size,
                              hipStream_t stream)
{
  const float* adj    = (const float*)d_in[0];  // [6400, 6400]
  const float* feat   = (const float*)d_in[1];  // [6400, 128]
  const float* weight = (const float*)d_in[2];  // [128, 128]
  const float* rew    = (const float*)d_in[3];  // [200, 200]
  float*       out    = (float*)d_out;          // [6400, 128]

  short*    supp  = (short*)d_ws;                         // 1,835,008 B
  float*    msk   = (float*)((char*)d_ws + 1835008);      //   179,200 B
  unsigned* flags = (unsigned*)((char*)d_ws + 2014208);   //       928 B

  fused_kernel<<<488, 256, 0, stream>>>(feat, weight, rew, adj,
                                        supp, msk, flags, out);
}

// Round 6
// 18.145 us; speedup vs baseline: 2.9244x; 2.9244x over previous
//
#include <hip/hip_runtime.h>
#include <hip/hip_bf16.h>

#define NN 6400   // total nodes
#define NG 200    // nodes per graph
#define NB 32     // graphs
#define FF 128    // F_in == F_out

typedef __attribute__((ext_vector_type(8))) short s8v;  // 8 x bf16 (4 VGPRs)
typedef __attribute__((ext_vector_type(4))) float f4v;  // MFMA accumulator

__device__ __forceinline__ short f2bf(float x) {
  unsigned u = __float_as_uint(x);
  u += 0x7FFFu + ((u >> 16) & 1u);   // RNE
  return (short)(u >> 16);
}
__device__ __forceinline__ float sigm(float x) {
  return __builtin_amdgcn_rcpf(1.f + __expf(-x));
}
// Bank-swizzle for sM granules (bijective within each 64-granule tile).
__device__ __forceinline__ int swz(int g) {
  return g ^ ((g >> 4) & 3) ^ ((g >> 6) & 7);
}

// LDS layout (bytes):
//   sSupp [0,      28672) : B-frags [kc=7][nt'=4][lane=64] x 16B  (this nh half)
//   sW    [28672,  45056) : B-frags [kc=4][nt'=4][lane=64] x 16B
//   sRT   [45056,  65456) : [25][204] f32 rew^T slice  (aliased by sM after use)
//   sM    [45056,  59392) : A-frags [mt=2][kc=7][lane=64] x 16B
#define LDS_BYTES 65456
#define RT_STRIDE 204

__global__ __launch_bounds__(256) void fused(
    const float* __restrict__ adj,  const float* __restrict__ feat,
    const float* __restrict__ weight, const float* __restrict__ rew,
    float* __restrict__ out)
{
  __shared__ char lds[LDS_BYTES];
  s8v*   sSupp = (s8v*)lds;
  s8v*   sW    = (s8v*)(lds + 28672);
  float* sRT   = (float*)(lds + 45056);
  s8v*   sM    = (s8v*)(lds + 45056);

  const int t   = threadIdx.x;
  const int bid = blockIdx.x;
  // decode so a graph's 16 blocks share one XCD (bid%8 const per graph)
  const int lo = bid & 7, mid = (bid >> 3) & 15, hi = bid >> 7;
  const int b = lo + 8 * hi;           // graph 0..31
  const int slab = mid >> 1;           // 0..7 (25 rows each)
  const int nh   = mid & 1;            // column half 0..1
  const int i0   = slab * 25;

  // ---- phase 0a: issue adj prefetch (raw values; sigmoid later) ----
  float4 pa0[4], pa1[4];
  bool okf[4];
#pragma unroll
  for (int p = 0; p < 4; ++p) {
    const int idx = t + p * 256;
    const int i = idx / 28, jg = idx - i * 28;
    okf[p] = (idx < 896) & (jg < 25) & (i < 25);
    if (okf[p]) {
      const float* ap = adj + ((size_t)(b * NG + i0 + i) * NN + b * NG + jg * 8);
      pa0[p] = *(const float4*)ap;
      pa1[p] = *(const float4*)(ap + 4);
    }
  }

  // ---- phase 0b: zero K-pad slots of sSupp (kc=6, lanes 16..63 = kloc 200..223)
  if (t < 192) {
    const int nt = t / 48, lane = 16 + (t % 48);
    sSupp[(6 * 4 + nt) * 64 + lane] = (s8v){0,0,0,0,0,0,0,0};
  }

  // ---- phase 0c: rew rows -> sRT transpose slice (cols i0..i0+24) ----
  {
    const int col0 = (i0 > NG - 28) ? ((NG - 28) & ~3) : (i0 & ~3);  // 16B-aligned
    for (int p = 0; p < 6; ++p) {
      const int idx = t + p * 256;              // 200 rows x 7 float4
      if (idx < 1400) {
        const int j = idx / 7, f4 = idx - j * 7;
        const float4 v = *(const float4*)&rew[j * NG + col0 + f4 * 4];
#pragma unroll
        for (int e = 0; e < 4; ++e) {
          const int c = col0 + f4 * 4 + e - i0;
          if (0 <= c && c < 25) sRT[c * RT_STRIDE + j] = ((const float*)&v)[e];
        }
      }
    }
  }

  // ---- phase 0d: W -> sW B-frags (cols nh*64 .. +63) ----
  for (int p = 0; p < 4; ++p) {
    const int idx = t + p * 256;                // 1024 granules
    const int n4 = idx & 63, kg = idx >> 6;     // n' in [0,64), kg in [0,16)
    s8v v;
#pragma unroll
    for (int e = 0; e < 8; ++e)
      v[e] = f2bf(weight[(kg * 8 + e) * FF + nh * 64 + n4]);
    sW[((kg >> 2) * 4 + (n4 >> 4)) * 64 + (n4 & 15) + (kg & 3) * 16] = v;
  }
  __syncthreads();

  // ---- phase 1a: M values -> regs (sigmoid(adj) * (0.5(R+R^T)+I)) ----
  s8v vM[4];
#pragma unroll
  for (int p = 0; p < 4; ++p) {
    s8v v = (s8v){0,0,0,0,0,0,0,0};
    if (okf[p]) {
      const int idx = t + p * 256;
      const int i = idx / 28, jg = idx - i * 28;
      const int gi = i0 + i;
      const float* rp = rew + gi * NG + jg * 8;
      const float4 r0 = *(const float4*)rp;
      const float4 r1 = *(const float4*)(rp + 4);
      const float4 t0 = *(const float4*)&sRT[i * RT_STRIDE + jg * 8];
      const float4 t1 = *(const float4*)&sRT[i * RT_STRIDE + jg * 8 + 4];
      const int jd = gi - jg * 8;               // diagonal when jd == e
      v[0] = f2bf((0.5f*(r0.x + t0.x) + (jd==0)) * sigm(pa0[p].x));
      v[1] = f2bf((0.5f*(r0.y + t0.y) + (jd==1)) * sigm(pa0[p].y));
      v[2] = f2bf((0.5f*(r0.z + t0.z) + (jd==2)) * sigm(pa0[p].z));
      v[3] = f2bf((0.5f*(r0.w + t0.w) + (jd==3)) * sigm(pa0[p].w));
      v[4] = f2bf((0.5f*(r1.x + t1.x) + (jd==4)) * sigm(pa1[p].x));
      v[5] = f2bf((0.5f*(r1.y + t1.y) + (jd==5)) * sigm(pa1[p].y));
      v[6] = f2bf((0.5f*(r1.z + t1.z) + (jd==6)) * sigm(pa1[p].z));
      v[7] = f2bf((0.5f*(r1.w + t1.w) + (jd==7)) * sigm(pa1[p].w));
    }
    vM[p] = v;
  }

  // ---- phase 1b: support(this half) = feat_b @ W[:,half]  -> sSupp B-frags ----
  const int l = t & 63, w = t >> 6;             // 4 waves
  for (int m = w; m < 13; m += 4) {             // 13 row-tiles of 16 (200 rows)
    int local = m * 16 + (l & 15);
    if (local > 199) local = 199;               // clamp: D rows >=200 not stored
    const float* frow = feat + ((size_t)(b * NG) + local) * FF;

    f4v a0 = {0.f,0.f,0.f,0.f}, a1 = a0, a2 = a0, a3 = a0;
#pragma unroll
    for (int kc = 0; kc < 4; ++kc) {
      const float* fp = frow + kc * 32 + (l >> 4) * 8;
      const float4 fa = *(const float4*)fp;
      const float4 fb = *(const float4*)(fp + 4);
      s8v af;
      af[0]=f2bf(fa.x); af[1]=f2bf(fa.y); af[2]=f2bf(fa.z); af[3]=f2bf(fa.w);
      af[4]=f2bf(fb.x); af[5]=f2bf(fb.y); af[6]=f2bf(fb.z); af[7]=f2bf(fb.w);
      a0 = __builtin_amdgcn_mfma_f32_16x16x32_bf16(af, sW[(kc*4 + 0)*64 + l], a0, 0,0,0);
      a1 = __builtin_amdgcn_mfma_f32_16x16x32_bf16(af, sW[(kc*4 + 1)*64 + l], a1, 0,0,0);
      a2 = __builtin_amdgcn_mfma_f32_16x16x32_bf16(af, sW[(kc*4 + 2)*64 + l], a2, 0,0,0);
      a3 = __builtin_amdgcn_mfma_f32_16x16x32_bf16(af, sW[(kc*4 + 3)*64 + l], a3, 0,0,0);
    }
    // scatter D (col=l&15, row=(l>>4)*4+reg) into B-frag layout
#pragma unroll
    for (int reg = 0; reg < 4; ++reg) {
      const int kloc = m * 16 + (l >> 4) * 4 + reg;
      if (kloc < 200) {
        const int lane = (l & 15) + ((kloc >> 3) & 3) * 16;
        const int e = kloc & 7;
        ((short*)&sSupp[((kloc >> 5) * 4 + 0) * 64 + lane])[e] = f2bf(a0[reg]);
        ((short*)&sSupp[((kloc >> 5) * 4 + 1) * 64 + lane])[e] = f2bf(a1[reg]);
        ((short*)&sSupp[((kloc >> 5) * 4 + 2) * 64 + lane])[e] = f2bf(a2[reg]);
        ((short*)&sSupp[((kloc >> 5) * 4 + 3) * 64 + lane])[e] = f2bf(a3[reg]);
      }
    }
  }
  __syncthreads();   // sRT reads done; sSupp complete

  // ---- phase 2: write sM A-frags (aliases the dead sRT region) ----
#pragma unroll
  for (int p = 0; p < 4; ++p) {
    const int idx = t + p * 256;
    if (idx < 896) {
      const int i = idx / 28, jg = idx - i * 28;
      const int g = ((i >> 4) * 7 + (jg >> 2)) * 64 + (i & 15) + (jg & 3) * 16;
      sM[swz(g)] = vM[p];
    }
  }
  __syncthreads();

  // ---- phase 3: out-slab = M @ support   (pure LDS MFMA) ----
  const int mt = w >> 1, ntp = w & 1;           // wave -> (row-tile, nt-pair)
  f4v o0 = {0.f,0.f,0.f,0.f}, o1 = o0;
#pragma unroll
  for (int kc = 0; kc < 7; ++kc) {
    const s8v af = sM[swz((mt * 7 + kc) * 64 + l)];
    o0 = __builtin_amdgcn_mfma_f32_16x16x32_bf16(af, sSupp[(kc*4 + ntp*2 + 0)*64 + l], o0, 0,0,0);
    o1 = __builtin_amdgcn_mfma_f32_16x16x32_bf16(af, sSupp[(kc*4 + ntp*2 + 1)*64 + l], o1, 0,0,0);
  }
#pragma unroll
  for (int reg = 0; reg < 4; ++reg) {
    const int rl = mt * 16 + (l >> 4) * 4 + reg;
    if (rl < 25) {
      const size_t o = (size_t)(b * NG + i0 + rl) * FF + nh * 64 + (l & 15);
      out[o + (ntp * 2 + 0) * 16] = o0[reg];
      out[o + (ntp * 2 + 1) * 16] = o1[reg];
    }
  }
}

// ---------------------------------------------------------------------------
extern "C" void kernel_launch(void* const* d_in, const int* in_sizes, int n_in,
                              void* d_out, int out_size, void* d_ws, size_t ws_size,
                              hipStream_t stream)
{
  const float* adj    = (const float*)d_in[0];  // [6400, 6400]
  const float* feat   = (const float*)d_in[1];  // [6400, 128]
  const float* weight = (const float*)d_in[2];  // [128, 128]
  const float* rew    = (const float*)d_in[3];  // [200, 200]
  float*       out    = (float*)d_out;          // [6400, 128]

  fused<<<512, 256, 0, stream>>>(adj, feat, weight, rew, out);
}